// Round 1
// baseline (227.428 us; speedup 1.0000x reference)
//
#include <hip/hip_runtime.h>
#include <stdint.h>

#define N_NODES 8192
#define N_EDGES 65536
#define N_TRIPLES (N_EDGES + N_NODES)   // 73728
#define D 768
#define D2 1536
#define NREL 38
#define BATCH 8
#define SENTN 512                        // B*S
#define OUT1_OFF ((size_t)N_TRIPLES * D)                     // 56623104
#define OUT2_OFF (OUT1_OFF + (size_t)BATCH * N_TRIPLES)      // 57212928

typedef __attribute__((ext_vector_type(8))) __bf16 bf16x8;
typedef __attribute__((ext_vector_type(4))) float f32x4;
typedef __attribute__((ext_vector_type(4))) unsigned short ushort4v;

static __device__ __forceinline__ unsigned short f2bf(float f) {
  unsigned u = __builtin_bit_cast(unsigned, f);
  u += 0x7FFFu + ((u >> 16) & 1u);
  return (unsigned short)(u >> 16);
}

// ---------------- prep: x = bf16(concept_embedding[concept_ids]) ----------------
__global__ void k_prep_x(const int* __restrict__ cids, const float* __restrict__ cemb,
                         unsigned short* __restrict__ xbf) {
  int t4 = blockIdx.x * blockDim.x + threadIdx.x;   // one float4 per thread
  if (t4 >= N_NODES * (D / 4)) return;
  int row = t4 / (D / 4);
  int c4 = t4 % (D / 4);
  int cid = cids[row];
  float4 v = ((const float4*)(cemb + (size_t)cid * D))[c4];
  ushort4v o;
  o.x = f2bf(v.x); o.y = f2bf(v.y); o.z = f2bf(v.z); o.w = f2bf(v.w);
  *(ushort4v*)(xbf + (size_t)t4 * 4) = o;
}

// ---------------- prep: W13T[j][k] = bf16(W1|W3 transposed) ----------------
// j<768:  W13T[j][k] = W[k][j]          (W1)
// j>=768: W13T[j][k] = W[1536+k][j-768] (W3)
__global__ void k_prep_w(const float* __restrict__ W, unsigned short* __restrict__ wt) {
  __shared__ float tile[32][33];
  int kb = blockIdx.x * 32;
  int jb = blockIdx.y * 32;
  int tx = threadIdx.x % 32;
  int ty = threadIdx.x / 32;
#pragma unroll
  for (int i = 0; i < 4; ++i) {
    int k = kb + ty + i * 8;
    int j = jb + tx;
    float v = (j < D) ? W[(size_t)k * D + j] : W[(size_t)(2 * D + k) * D + (j - D)];
    tile[ty + i * 8][tx] = v;
  }
  __syncthreads();
#pragma unroll
  for (int i = 0; i < 4; ++i) {
    int j = jb + ty + i * 8;
    int k = kb + tx;
    wt[(size_t)j * D + k] = f2bf(tile[tx][ty + i * 8]);
  }
}

// ---------------- relW2[r][c] = sum_k src_r[k] * W[768+k][c];  r==38 -> self loop ----------------
__global__ void k_relw2(const float* __restrict__ relemb, const float* __restrict__ selfemb,
                        const float* __restrict__ W, float* __restrict__ relw2) {
  int r = blockIdx.x;  // 0..38
  const float* src = (r < NREL) ? (relemb + (size_t)r * D) : selfemb;
  int c = threadIdx.x;  // 256 threads, 3 cols each
  const float* W2 = W + (size_t)D * D;
  float a0 = 0.f, a1 = 0.f, a2 = 0.f;
  for (int k = 0; k < D; ++k) {
    float s = src[k];
    const float* wr = W2 + (size_t)k * D;
    a0 += s * wr[c];
    a1 += s * wr[c + 256];
    a2 += s * wr[c + 512];
  }
  relw2[(size_t)r * D + c] = a0;
  relw2[(size_t)r * D + c + 256] = a1;
  relw2[(size_t)r * D + c + 512] = a2;
}

// ---------------- node_mask[n]: bit b set if concept_ids[n] in sent batch b ----------------
__global__ void k_nodemask(const int* __restrict__ cids, const int* __restrict__ sent,
                           unsigned int* __restrict__ nmask) {
  __shared__ int ls[SENTN];
  for (int i = threadIdx.x; i < SENTN; i += blockDim.x) ls[i] = sent[i];
  __syncthreads();
  int n = blockIdx.x * blockDim.x + threadIdx.x;
  if (n >= N_NODES) return;
  int cid = cids[n];
  unsigned m = 0;
#pragma unroll 16
  for (int s = 0; s < SENTN; ++s)
    m |= (ls[s] == cid) ? (1u << (s >> 6)) : 0u;
  nmask[n] = m;
}

// ---------------- GEMM: C[8192][1536] = A[8192][768](bf16) * BT[1536][768](bf16)^T ----------------
__global__ void k_gemm(const unsigned short* __restrict__ A,
                       const unsigned short* __restrict__ BT,
                       float* __restrict__ C) {
  __shared__ __align__(16) unsigned short lsA[128 * 64];
  __shared__ __align__(16) unsigned short lsB[128 * 64];
  const int tid = threadIdx.x;
  const int lane = tid & 63;
  const int wid = tid >> 6;
  const int wr = wid >> 1, wc = wid & 1;
  const int arow0 = blockIdx.y * 128;
  const int bcol0 = blockIdx.x * 128;

  f32x4 acc[4][4] = {};

  const int rloc = tid >> 3;           // 0..31: row within 32-row chunk
  const int c8 = (tid & 7) * 8;        // 8-elem column offset
  const unsigned short* ga = A + (size_t)(arow0 + rloc) * D + c8;
  const unsigned short* gb = BT + (size_t)(bcol0 + rloc) * D + c8;
  unsigned short* lbaseA = lsA + (size_t)(tid & ~63) * 8;
  unsigned short* lbaseB = lsB + (size_t)(tid & ~63) * 8;

  for (int k0 = 0; k0 < D; k0 += 64) {
    __syncthreads();
#pragma unroll
    for (int c = 0; c < 4; ++c) {
      __builtin_amdgcn_global_load_lds(
          (const __attribute__((address_space(1))) void*)(ga + (size_t)c * 32 * D + k0),
          (__attribute__((address_space(3))) void*)(lbaseA + c * 2048), 16, 0, 0);
      __builtin_amdgcn_global_load_lds(
          (const __attribute__((address_space(1))) void*)(gb + (size_t)c * 32 * D + k0),
          (__attribute__((address_space(3))) void*)(lbaseB + c * 2048), 16, 0, 0);
    }
    asm volatile("s_waitcnt vmcnt(0)" ::: "memory");
    __syncthreads();

#pragma unroll
    for (int kk = 0; kk < 2; ++kk) {
      const int lr = lane & 15;
      const int lk = kk * 32 + (lane >> 4) * 8;
      bf16x8 af[4], bfr[4];
#pragma unroll
      for (int m = 0; m < 4; ++m)
        af[m] = *(const bf16x8*)(lsA + (wr * 64 + m * 16 + lr) * 64 + lk);
#pragma unroll
      for (int n = 0; n < 4; ++n)
        bfr[n] = *(const bf16x8*)(lsB + (wc * 64 + n * 16 + lr) * 64 + lk);
#pragma unroll
      for (int m = 0; m < 4; ++m)
#pragma unroll
        for (int n = 0; n < 4; ++n)
          acc[m][n] = __builtin_amdgcn_mfma_f32_16x16x32_bf16(af[m], bfr[n], acc[m][n], 0, 0, 0);
    }
  }

  const int crow = (lane >> 4) * 4;
  const int ccol = lane & 15;
#pragma unroll
  for (int m = 0; m < 4; ++m) {
    int row = arow0 + wr * 64 + m * 16 + crow;
#pragma unroll
    for (int n = 0; n < 4; ++n) {
      int col = bcol0 + wc * 64 + n * 16 + ccol;
      float* cp = C + (size_t)row * D2 + col;
#pragma unroll
      for (int r = 0; r < 4; ++r)
        cp[(size_t)r * D2] = acc[m][n][r];
    }
  }
}

// ---------------- epilogue: encoded[t] = xW1[head] + w*relW2[rel] + xW3[tail] + b ----------------
__global__ void k_encode(const int* __restrict__ eidx, const float* __restrict__ eattr,
                         const float* __restrict__ xw, const float* __restrict__ relw2,
                         const float* __restrict__ bias, float* __restrict__ out0) {
  int wid = threadIdx.x >> 6;
  int lane = threadIdx.x & 63;
  int t = blockIdx.x * 4 + wid;
  const float4 *r1, *r3, *rw;
  float w;
  if (t < N_EDGES) {
    int h = eidx[t];
    int tl = eidx[N_EDGES + t];
    int rel = (int)eattr[2 * t];
    w = eattr[2 * t + 1];
    r1 = (const float4*)(xw + (size_t)h * D2);
    r3 = (const float4*)(xw + (size_t)tl * D2 + D);
    rw = (const float4*)(relw2 + (size_t)rel * D);
  } else {
    int i = t - N_EDGES;
    w = 1.f;
    r1 = (const float4*)(xw + (size_t)i * D2);
    r3 = (const float4*)(xw + (size_t)i * D2 + D);
    rw = (const float4*)(relw2 + (size_t)NREL * D);
  }
  const float4* bv = (const float4*)bias;
  float4* o = (float4*)(out0 + (size_t)t * D);
#pragma unroll
  for (int j = 0; j < 3; ++j) {
    int c4 = j * 64 + lane;
    float4 a = r1[c4], x3 = r3[c4], c = rw[c4], d = bv[c4];
    float4 res;
    res.x = a.x + w * c.x + x3.x + d.x;
    res.y = a.y + w * c.y + x3.y + d.y;
    res.z = a.z + w * c.z + x3.z + d.z;
    res.w = a.w + w * c.w + x3.w + d.w;
    o[c4] = res;
  }
}

// ---------------- ids + mask outputs ----------------
__global__ void k_idsmask(const int* __restrict__ cids, const int* __restrict__ eidx,
                          const float* __restrict__ eattr, const unsigned* __restrict__ nmask,
                          float* __restrict__ out) {
  int t = blockIdx.x * blockDim.x + threadIdx.x;
  if (t >= N_TRIPLES) return;
  int h, tl;
  float rel;
  if (t < N_EDGES) {
    h = eidx[t];
    tl = eidx[N_EDGES + t];
    rel = (float)(int)eattr[2 * t];
  } else {
    h = t - N_EDGES;
    tl = h;
    rel = (float)NREL;
  }
  float* o2 = out + OUT2_OFF + (size_t)t * 3;
  o2[0] = (float)cids[h];
  o2[1] = rel;
  o2[2] = (float)cids[tl];
  unsigned m = nmask[h] | nmask[tl];
  float* o1 = out + OUT1_OFF;
#pragma unroll
  for (int b = 0; b < BATCH; ++b)
    o1[(size_t)b * N_TRIPLES + t] = ((m >> b) & 1u) ? 1.0f : 0.0f;
}

extern "C" void kernel_launch(void* const* d_in, const int* in_sizes, int n_in,
                              void* d_out, int out_size, void* d_ws, size_t ws_size,
                              hipStream_t stream) {
  const int* cids = (const int*)d_in[0];
  const int* eidx = (const int*)d_in[1];
  const float* eattr = (const float*)d_in[2];
  const int* sent = (const int*)d_in[3];
  const float* cemb = (const float*)d_in[4];
  const float* relemb = (const float*)d_in[5];
  const float* selfemb = (const float*)d_in[6];
  const float* W = (const float*)d_in[7];
  const float* bias = (const float*)d_in[8];

  char* ws = (char*)d_ws;
  unsigned short* xbf = (unsigned short*)ws;                        // 12,582,912 B
  unsigned short* wt = (unsigned short*)(ws + 12582912);            //  2,359,296 B
  float* xw = (float*)(ws + 12582912 + 2359296);                    // 50,331,648 B
  float* relw2 = (float*)(ws + 12582912 + 2359296 + 50331648);      //    119,808 B
  unsigned* nmask = (unsigned*)(ws + 12582912 + 2359296 + 50331648 + 119808);  // 32 KB

  float* out = (float*)d_out;

  k_prep_x<<<dim3(6144), dim3(256), 0, stream>>>(cids, cemb, xbf);
  k_prep_w<<<dim3(24, 48), dim3(256), 0, stream>>>(W, wt);
  k_relw2<<<dim3(39), dim3(256), 0, stream>>>(relemb, selfemb, W, relw2);
  k_nodemask<<<dim3(32), dim3(256), 0, stream>>>(cids, sent, nmask);
  k_gemm<<<dim3(12, 64), dim3(256), 0, stream>>>(xbf, wt, xw);
  k_encode<<<dim3(N_TRIPLES / 4), dim3(256), 0, stream>>>(eidx, eattr, xw, relw2, bias, out);
  k_idsmask<<<dim3(288), dim3(256), 0, stream>>>(cids, eidx, eattr, nmask, out);
}

// Round 2
// 162.736 us; speedup vs baseline: 1.3975x; 1.3975x over previous
//
#include <hip/hip_runtime.h>
#include <stdint.h>

#define N_NODES 8192
#define N_EDGES 65536
#define N_TRIPLES (N_EDGES + N_NODES)   // 73728
#define D 768
#define D2 1536
#define NREL 38
#define BATCH 8
#define SENTN 512                        // B*S
#define OUT1_OFF ((size_t)N_TRIPLES * D)                     // 56623104
#define OUT2_OFF (OUT1_OFF + (size_t)BATCH * N_TRIPLES)      // 57212928

typedef __attribute__((ext_vector_type(8))) __bf16 bf16x8;
typedef __attribute__((ext_vector_type(4))) float f32x4;
typedef __attribute__((ext_vector_type(4))) unsigned short ushort4v;

static __device__ __forceinline__ unsigned short f2bf(float f) {
  unsigned u = __builtin_bit_cast(unsigned, f);
  u += 0x7FFFu + ((u >> 16) & 1u);
  return (unsigned short)(u >> 16);
}
static __device__ __forceinline__ float bf2f(unsigned short h) {
  return __builtin_bit_cast(float, ((unsigned)h) << 16);
}

// ================= merged prep =================
// blocks [0,6144): x = bf16(cemb[cids])           (one float4 per thread)
// blocks [6144,7296): W13T transpose->bf16
// blocks [7296,7335): relW2 rows (38 rels + self loop)
// blocks [7335,7367): node mask bits
__global__ void k_prep(const int* __restrict__ cids, const float* __restrict__ cemb,
                       unsigned short* __restrict__ xbf,
                       const float* __restrict__ W, unsigned short* __restrict__ wt,
                       const float* __restrict__ relemb, const float* __restrict__ selfemb,
                       float* __restrict__ relw2,
                       const int* __restrict__ sent, unsigned int* __restrict__ nmask) {
  __shared__ __align__(16) char smraw[32 * 33 * 4];
  int b = blockIdx.x;
  if (b < 6144) {
    int t4 = b * 256 + threadIdx.x;
    int row = t4 / (D / 4);
    int c4 = t4 % (D / 4);
    int cid = cids[row];
    float4 v = ((const float4*)(cemb + (size_t)cid * D))[c4];
    ushort4v o;
    o.x = f2bf(v.x); o.y = f2bf(v.y); o.z = f2bf(v.z); o.w = f2bf(v.w);
    *(ushort4v*)(xbf + (size_t)t4 * 4) = o;
  } else if (b < 7296) {
    float (*tile)[33] = (float(*)[33])smraw;
    int idx = b - 6144;
    int kb = (idx % 24) * 32;
    int jb = (idx / 24) * 32;
    int tx = threadIdx.x % 32;
    int ty = threadIdx.x / 32;
#pragma unroll
    for (int i = 0; i < 4; ++i) {
      int k = kb + ty + i * 8;
      int j = jb + tx;
      float v = (j < D) ? W[(size_t)k * D + j] : W[(size_t)(2 * D + k) * D + (j - D)];
      tile[ty + i * 8][tx] = v;
    }
    __syncthreads();
#pragma unroll
    for (int i = 0; i < 4; ++i) {
      int j = jb + ty + i * 8;
      int k = kb + tx;
      wt[(size_t)j * D + k] = f2bf(tile[tx][ty + i * 8]);
    }
  } else if (b < 7335) {
    int r = b - 7296;  // 0..38
    const float* src = (r < NREL) ? (relemb + (size_t)r * D) : selfemb;
    int c = threadIdx.x;
    const float* W2 = W + (size_t)D * D;
    float a0 = 0.f, a1 = 0.f, a2 = 0.f;
    for (int k = 0; k < D; ++k) {
      float s = src[k];
      const float* wr = W2 + (size_t)k * D;
      a0 += s * wr[c];
      a1 += s * wr[c + 256];
      a2 += s * wr[c + 512];
    }
    relw2[(size_t)r * D + c] = a0;
    relw2[(size_t)r * D + c + 256] = a1;
    relw2[(size_t)r * D + c + 512] = a2;
  } else {
    int* ls = (int*)smraw;
    for (int i = threadIdx.x; i < SENTN; i += 256) ls[i] = sent[i];
    __syncthreads();
    int n = (b - 7335) * 256 + threadIdx.x;
    int cid = cids[n];
    unsigned m = 0;
#pragma unroll 16
    for (int s = 0; s < SENTN; ++s)
      m |= (ls[s] == cid) ? (1u << (s >> 6)) : 0u;
    nmask[n] = m;
  }
}

// ================= GEMM: Cb[8192][1536](bf16) = A[8192][768](bf16) * BT[1536][768]^T =================
// LDS staged via global_load_lds (linear dest) with SOURCE-side XOR swizzle (chunk ^= row&7),
// reads apply the same XOR -> 2-way banks instead of 16-way.
__global__ void k_gemm(const unsigned short* __restrict__ A,
                       const unsigned short* __restrict__ BT,
                       unsigned short* __restrict__ Cb) {
  __shared__ __align__(16) unsigned short lsA[128 * 64];
  __shared__ __align__(16) unsigned short lsB[128 * 64];
  const int tid = threadIdx.x;
  const int lane = tid & 63;
  const int wid = tid >> 6;
  const int wr = wid >> 1, wc = wid & 1;
  const int arow0 = blockIdx.y * 128;
  const int bcol0 = blockIdx.x * 128;

  f32x4 acc[4][4] = {};

  const int rloc = tid >> 3;                       // 0..31: row within 32-row chunk
  const int gchunk = (tid & 7) ^ (rloc & 7);       // swizzled source col-chunk
  const unsigned short* ga = A + (size_t)(arow0 + rloc) * D + gchunk * 8;
  const unsigned short* gb = BT + (size_t)(bcol0 + rloc) * D + gchunk * 8;
  unsigned short* lbaseA = lsA + (size_t)(tid & ~63) * 8;
  unsigned short* lbaseB = lsB + (size_t)(tid & ~63) * 8;

  const int lr = lane & 15;
  const int hi = lane >> 4;

  for (int k0 = 0; k0 < D; k0 += 64) {
    __syncthreads();
#pragma unroll
    for (int c = 0; c < 4; ++c) {
      __builtin_amdgcn_global_load_lds(
          (const __attribute__((address_space(1))) void*)(ga + (size_t)c * 32 * D + k0),
          (__attribute__((address_space(3))) void*)(lbaseA + c * 2048), 16, 0, 0);
      __builtin_amdgcn_global_load_lds(
          (const __attribute__((address_space(1))) void*)(gb + (size_t)c * 32 * D + k0),
          (__attribute__((address_space(3))) void*)(lbaseB + c * 2048), 16, 0, 0);
    }
    asm volatile("s_waitcnt vmcnt(0)" ::: "memory");
    __syncthreads();

#pragma unroll
    for (int kk = 0; kk < 2; ++kk) {
      const int swz = ((kk * 4 + hi) ^ (lr & 7)) * 8;   // swizzled read chunk
      bf16x8 af[4], bfr[4];
#pragma unroll
      for (int m = 0; m < 4; ++m)
        af[m] = *(const bf16x8*)(lsA + (wr * 64 + m * 16 + lr) * 64 + swz);
#pragma unroll
      for (int n = 0; n < 4; ++n)
        bfr[n] = *(const bf16x8*)(lsB + (wc * 64 + n * 16 + lr) * 64 + swz);
#pragma unroll
      for (int m = 0; m < 4; ++m)
#pragma unroll
        for (int n = 0; n < 4; ++n)
          acc[m][n] = __builtin_amdgcn_mfma_f32_16x16x32_bf16(af[m], bfr[n], acc[m][n], 0, 0, 0);
    }
  }

  const int crow = (lane >> 4) * 4;
  const int ccol = lane & 15;
#pragma unroll
  for (int m = 0; m < 4; ++m) {
    int row = arow0 + wr * 64 + m * 16 + crow;
#pragma unroll
    for (int n = 0; n < 4; ++n) {
      int col = bcol0 + wc * 64 + n * 16 + ccol;
      unsigned short* cp = Cb + (size_t)row * D2 + col;
#pragma unroll
      for (int r = 0; r < 4; ++r)
        cp[(size_t)r * D2] = f2bf(acc[m][n][r]);
    }
  }
}

// ================= outputs: encoded + mask + ids =================
// blocks [0,18432): encoded[t] = xw1[head] + w*relW2[rel] + xw3[tail] + b  (4 triples/block)
// blocks [18432,18720): triple_ids + mask (256 triples/block)
__global__ void k_out(const int* __restrict__ cids, const int* __restrict__ eidx,
                      const float* __restrict__ eattr, const unsigned short* __restrict__ xwb,
                      const float* __restrict__ relw2, const float* __restrict__ bias,
                      const unsigned* __restrict__ nmask, float* __restrict__ out) {
  int b = blockIdx.x;
  if (b < 18432) {
    int wid = threadIdx.x >> 6;
    int lane = threadIdx.x & 63;
    int t = b * 4 + wid;
    const ushort4v *r1, *r3;
    const float4* rw;
    float w;
    if (t < N_EDGES) {
      int h = eidx[t];
      int tl = eidx[N_EDGES + t];
      int rel = (int)eattr[2 * t];
      w = eattr[2 * t + 1];
      r1 = (const ushort4v*)(xwb + (size_t)h * D2);
      r3 = (const ushort4v*)(xwb + (size_t)tl * D2 + D);
      rw = (const float4*)(relw2 + (size_t)rel * D);
    } else {
      int i = t - N_EDGES;
      w = 1.f;
      r1 = (const ushort4v*)(xwb + (size_t)i * D2);
      r3 = (const ushort4v*)(xwb + (size_t)i * D2 + D);
      rw = (const float4*)(relw2 + (size_t)NREL * D);
    }
    const float4* bv = (const float4*)bias;
    float4* o = (float4*)(out + (size_t)t * D);
#pragma unroll
    for (int j = 0; j < 3; ++j) {
      int c4 = j * 64 + lane;
      ushort4v a4 = r1[c4], x4 = r3[c4];
      float4 c = rw[c4], dd = bv[c4];
      float4 res;
      res.x = bf2f(a4.x) + w * c.x + bf2f(x4.x) + dd.x;
      res.y = bf2f(a4.y) + w * c.y + bf2f(x4.y) + dd.y;
      res.z = bf2f(a4.z) + w * c.z + bf2f(x4.z) + dd.z;
      res.w = bf2f(a4.w) + w * c.w + bf2f(x4.w) + dd.w;
      o[c4] = res;
    }
  } else {
    int t = (b - 18432) * 256 + threadIdx.x;
    int h, tl;
    float rel;
    if (t < N_EDGES) {
      h = eidx[t];
      tl = eidx[N_EDGES + t];
      rel = (float)(int)eattr[2 * t];
    } else {
      h = t - N_EDGES;
      tl = h;
      rel = (float)NREL;
    }
    float* o2 = out + OUT2_OFF + (size_t)t * 3;
    o2[0] = (float)cids[h];
    o2[1] = rel;
    o2[2] = (float)cids[tl];
    unsigned m = nmask[h] | nmask[tl];
    float* o1 = out + OUT1_OFF;
#pragma unroll
    for (int bb = 0; bb < BATCH; ++bb)
      o1[(size_t)bb * N_TRIPLES + t] = ((m >> bb) & 1u) ? 1.0f : 0.0f;
  }
}

extern "C" void kernel_launch(void* const* d_in, const int* in_sizes, int n_in,
                              void* d_out, int out_size, void* d_ws, size_t ws_size,
                              hipStream_t stream) {
  const int* cids = (const int*)d_in[0];
  const int* eidx = (const int*)d_in[1];
  const float* eattr = (const float*)d_in[2];
  const int* sent = (const int*)d_in[3];
  const float* cemb = (const float*)d_in[4];
  const float* relemb = (const float*)d_in[5];
  const float* selfemb = (const float*)d_in[6];
  const float* W = (const float*)d_in[7];
  const float* bias = (const float*)d_in[8];

  char* ws = (char*)d_ws;
  unsigned short* xbf = (unsigned short*)ws;                         // 12,582,912 B
  unsigned short* wt = (unsigned short*)(ws + 12582912);             //  2,359,296 B
  unsigned short* xwb = (unsigned short*)(ws + 12582912 + 2359296);  // 25,165,824 B (bf16)
  float* relw2 = (float*)(ws + 12582912 + 2359296 + 25165824);       //    119,808 B
  unsigned* nmask = (unsigned*)(ws + 12582912 + 2359296 + 25165824 + 119808);  // 32 KB

  float* out = (float*)d_out;

  k_prep<<<dim3(7367), dim3(256), 0, stream>>>(cids, cemb, xbf, W, wt, relemb, selfemb,
                                               relw2, sent, nmask);
  k_gemm<<<dim3(12, 64), dim3(256), 0, stream>>>(xbf, wt, xwb);
  k_out<<<dim3(18720), dim3(256), 0, stream>>>(cids, eidx, eattr, xwb, relw2, bias, nmask, out);
}

// Round 3
// 149.898 us; speedup vs baseline: 1.5172x; 1.0856x over previous
//
#include <hip/hip_runtime.h>
#include <stdint.h>

#define N_NODES 8192
#define N_EDGES 65536
#define N_TRIPLES (N_EDGES + N_NODES)   // 73728
#define D 768
#define D2 1536
#define NREL 38
#define BATCH 8
#define SENTN 512                        // B*S
#define OUT1_OFF ((size_t)N_TRIPLES * D)                     // 56623104
#define OUT2_OFF (OUT1_OFF + (size_t)BATCH * N_TRIPLES)      // 57212928

typedef __attribute__((ext_vector_type(8))) __bf16 bf16x8;
typedef __attribute__((ext_vector_type(4))) float f32x4;
typedef __attribute__((ext_vector_type(4))) unsigned short ushort4v;

static __device__ __forceinline__ unsigned short f2bf(float f) {
  unsigned u = __builtin_bit_cast(unsigned, f);
  u += 0x7FFFu + ((u >> 16) & 1u);
  return (unsigned short)(u >> 16);
}
static __device__ __forceinline__ float bf2f(unsigned short h) {
  return __builtin_bit_cast(float, ((unsigned)h) << 16);
}

// ================= merged prep =================
// blocks [0,6144): x = bf16(cemb[cids])           (one float4 per thread)
// blocks [6144,7296): W13T transpose->bf16
// blocks [7296,7335): relW2 rows (38 rels + self loop)
// blocks [7335,7367): node mask bits
__global__ void k_prep(const int* __restrict__ cids, const float* __restrict__ cemb,
                       unsigned short* __restrict__ xbf,
                       const float* __restrict__ W, unsigned short* __restrict__ wt,
                       const float* __restrict__ relemb, const float* __restrict__ selfemb,
                       float* __restrict__ relw2,
                       const int* __restrict__ sent, unsigned int* __restrict__ nmask) {
  __shared__ __align__(16) char smraw[32 * 33 * 4];
  int b = blockIdx.x;
  if (b < 6144) {
    int t4 = b * 256 + threadIdx.x;
    int row = t4 / (D / 4);
    int c4 = t4 % (D / 4);
    int cid = cids[row];
    float4 v = ((const float4*)(cemb + (size_t)cid * D))[c4];
    ushort4v o;
    o.x = f2bf(v.x); o.y = f2bf(v.y); o.z = f2bf(v.z); o.w = f2bf(v.w);
    *(ushort4v*)(xbf + (size_t)t4 * 4) = o;
  } else if (b < 7296) {
    float (*tile)[33] = (float(*)[33])smraw;
    int idx = b - 6144;
    int kb = (idx % 24) * 32;
    int jb = (idx / 24) * 32;
    int tx = threadIdx.x % 32;
    int ty = threadIdx.x / 32;
#pragma unroll
    for (int i = 0; i < 4; ++i) {
      int k = kb + ty + i * 8;
      int j = jb + tx;
      float v = (j < D) ? W[(size_t)k * D + j] : W[(size_t)(2 * D + k) * D + (j - D)];
      tile[ty + i * 8][tx] = v;
    }
    __syncthreads();
#pragma unroll
    for (int i = 0; i < 4; ++i) {
      int j = jb + ty + i * 8;
      int k = kb + tx;
      wt[(size_t)j * D + k] = f2bf(tile[tx][ty + i * 8]);
    }
  } else if (b < 7335) {
    int r = b - 7296;  // 0..38
    const float* src = (r < NREL) ? (relemb + (size_t)r * D) : selfemb;
    int c = threadIdx.x;
    const float* W2 = W + (size_t)D * D;
    float a0 = 0.f, a1 = 0.f, a2 = 0.f;
    for (int k = 0; k < D; ++k) {
      float s = src[k];
      const float* wr = W2 + (size_t)k * D;
      a0 += s * wr[c];
      a1 += s * wr[c + 256];
      a2 += s * wr[c + 512];
    }
    relw2[(size_t)r * D + c] = a0;
    relw2[(size_t)r * D + c + 256] = a1;
    relw2[(size_t)r * D + c + 512] = a2;
  } else {
    int* ls = (int*)smraw;
    for (int i = threadIdx.x; i < SENTN; i += 256) ls[i] = sent[i];
    __syncthreads();
    int n = (b - 7335) * 256 + threadIdx.x;
    int cid = cids[n];
    unsigned m = 0;
#pragma unroll 16
    for (int s = 0; s < SENTN; ++s)
      m |= (ls[s] == cid) ? (1u << (s >> 6)) : 0u;
    nmask[n] = m;
  }
}

// ================= GEMM: Cb[8192][1536](bf16) = A[8192][768](bf16) * BT[1536][768]^T =================
// 2-phase double-buffered: stage tile t+1 BEFORE computing tile t; the barrier's
// mandatory vmcnt(0) drain then overlaps load latency with ds_read+MFMA.
// Source-side XOR swizzle (chunk ^= row&7) with linear LDS dest; reads apply same XOR.
__global__ void k_gemm(const unsigned short* __restrict__ A,
                       const unsigned short* __restrict__ BT,
                       unsigned short* __restrict__ Cb) {
  __shared__ __align__(16) unsigned short lsAB[2][2][128 * 64];   // [buf][A/B]
  const int tid = threadIdx.x;
  const int lane = tid & 63;
  const int wid = tid >> 6;
  const int wr = wid >> 1, wc = wid & 1;

  // XCD-aware bijective swizzle: 768 blocks, 96 per XCD; consecutive tiles in an
  // XCD share A-panels (8 panels = 1.5MB) + full B (2.4MB) -> fits 4MB L2.
  const int bid = blockIdx.x;
  const int swz = (bid & 7) * 96 + (bid >> 3);
  const int arow0 = (swz / 12) * 128;
  const int bcol0 = (swz % 12) * 128;

  f32x4 acc[4][4] = {};

  const int rloc = tid >> 3;                       // 0..31: row within 32-row chunk
  const int gchunk = (tid & 7) ^ (rloc & 7);       // swizzled source col-chunk
  const unsigned short* ga = A + (size_t)(arow0 + rloc) * D + gchunk * 8;
  const unsigned short* gb = BT + (size_t)(bcol0 + rloc) * D + gchunk * 8;
  const int lbo = (tid & ~63) * 8;                 // wave-uniform LDS elem offset

  const int lr = lane & 15;
  const int hi = lane >> 4;

#define STAGE(BUF, K0)                                                                 \
  {                                                                                    \
    unsigned short* dA = &lsAB[BUF][0][lbo];                                           \
    unsigned short* dB = &lsAB[BUF][1][lbo];                                           \
    _Pragma("unroll") for (int c = 0; c < 4; ++c) {                                    \
      __builtin_amdgcn_global_load_lds(                                                \
          (const __attribute__((address_space(1))) void*)(ga + (size_t)c * 32 * D + (K0)), \
          (__attribute__((address_space(3))) void*)(dA + c * 2048), 16, 0, 0);         \
      __builtin_amdgcn_global_load_lds(                                                \
          (const __attribute__((address_space(1))) void*)(gb + (size_t)c * 32 * D + (K0)), \
          (__attribute__((address_space(3))) void*)(dB + c * 2048), 16, 0, 0);         \
    }                                                                                  \
  }

#define COMPUTE(BUF)                                                                   \
  {                                                                                    \
    const unsigned short* sA = lsAB[BUF][0];                                           \
    const unsigned short* sB = lsAB[BUF][1];                                           \
    _Pragma("unroll") for (int kk = 0; kk < 2; ++kk) {                                 \
      const int swc = ((kk * 4 + hi) ^ (lr & 7)) * 8;                                  \
      bf16x8 af[4], bfr[4];                                                            \
      _Pragma("unroll") for (int m = 0; m < 4; ++m)                                    \
          af[m] = *(const bf16x8*)(sA + (wr * 64 + m * 16 + lr) * 64 + swc);           \
      _Pragma("unroll") for (int n = 0; n < 4; ++n)                                    \
          bfr[n] = *(const bf16x8*)(sB + (wc * 64 + n * 16 + lr) * 64 + swc);          \
      _Pragma("unroll") for (int m = 0; m < 4; ++m)                                    \
          _Pragma("unroll") for (int n = 0; n < 4; ++n)                                \
              acc[m][n] = __builtin_amdgcn_mfma_f32_16x16x32_bf16(af[m], bfr[n],       \
                                                                  acc[m][n], 0, 0, 0); \
    }                                                                                  \
  }

  STAGE(0, 0)
  __syncthreads();                 // barrier drains vmcnt+lgkm (compiler-emitted)
#pragma unroll
  for (int t = 0; t < 12; t += 2) {
    STAGE(1, (t + 1) * 64)         // prefetch next while computing current
    COMPUTE(0)
    __syncthreads();               // drains prefetch + all lds reads
    if (t + 2 < 12) STAGE(0, (t + 2) * 64)
    COMPUTE(1)
    __syncthreads();
  }
#undef STAGE
#undef COMPUTE

  const int crow = hi * 4;
  const int ccol = lr;
#pragma unroll
  for (int m = 0; m < 4; ++m) {
    int row = arow0 + wr * 64 + m * 16 + crow;
#pragma unroll
    for (int n = 0; n < 4; ++n) {
      int col = bcol0 + wc * 64 + n * 16 + ccol;
      unsigned short* cp = Cb + (size_t)row * D2 + col;
#pragma unroll
      for (int r = 0; r < 4; ++r)
        cp[(size_t)r * D2] = f2bf(acc[m][n][r]);
    }
  }
}

// ================= outputs: encoded + mask + ids =================
// All output writes nontemporal: 229MB streams bypass L2 so the 25MB xwb gather
// working set stays L2-resident for its ~9x reuse.
__global__ void k_out(const int* __restrict__ cids, const int* __restrict__ eidx,
                      const float* __restrict__ eattr, const unsigned short* __restrict__ xwb,
                      const float* __restrict__ relw2, const float* __restrict__ bias,
                      const unsigned* __restrict__ nmask, float* __restrict__ out) {
  int b = blockIdx.x;
  if (b < 18432) {
    int wid = threadIdx.x >> 6;
    int lane = threadIdx.x & 63;
    int t = b * 4 + wid;
    const ushort4v *r1, *r3;
    const f32x4* rw;
    float w;
    if (t < N_EDGES) {
      int h = eidx[t];
      int tl = eidx[N_EDGES + t];
      int rel = (int)eattr[2 * t];
      w = eattr[2 * t + 1];
      r1 = (const ushort4v*)(xwb + (size_t)h * D2);
      r3 = (const ushort4v*)(xwb + (size_t)tl * D2 + D);
      rw = (const f32x4*)(relw2 + (size_t)rel * D);
    } else {
      int i = t - N_EDGES;
      w = 1.f;
      r1 = (const ushort4v*)(xwb + (size_t)i * D2);
      r3 = (const ushort4v*)(xwb + (size_t)i * D2 + D);
      rw = (const f32x4*)(relw2 + (size_t)NREL * D);
    }
    const f32x4* bv = (const f32x4*)bias;
    f32x4* o = (f32x4*)(out + (size_t)t * D);
#pragma unroll
    for (int j = 0; j < 3; ++j) {
      int c4 = j * 64 + lane;
      ushort4v a4 = r1[c4], x4 = r3[c4];
      f32x4 c = rw[c4], dd = bv[c4];
      f32x4 res;
      res.x = bf2f(a4.x) + w * c.x + bf2f(x4.x) + dd.x;
      res.y = bf2f(a4.y) + w * c.y + bf2f(x4.y) + dd.y;
      res.z = bf2f(a4.z) + w * c.z + bf2f(x4.z) + dd.z;
      res.w = bf2f(a4.w) + w * c.w + bf2f(x4.w) + dd.w;
      __builtin_nontemporal_store(res, &o[c4]);
    }
  } else {
    int t = (b - 18432) * 256 + threadIdx.x;
    int h, tl;
    float rel;
    if (t < N_EDGES) {
      h = eidx[t];
      tl = eidx[N_EDGES + t];
      rel = (float)(int)eattr[2 * t];
    } else {
      h = t - N_EDGES;
      tl = h;
      rel = (float)NREL;
    }
    float* o2 = out + OUT2_OFF + (size_t)t * 3;
    __builtin_nontemporal_store((float)cids[h], o2 + 0);
    __builtin_nontemporal_store(rel, o2 + 1);
    __builtin_nontemporal_store((float)cids[tl], o2 + 2);
    unsigned m = nmask[h] | nmask[tl];
    float* o1 = out + OUT1_OFF;
#pragma unroll
    for (int bb = 0; bb < BATCH; ++bb)
      __builtin_nontemporal_store(((m >> bb) & 1u) ? 1.0f : 0.0f,
                                  o1 + (size_t)bb * N_TRIPLES + t);
  }
}

extern "C" void kernel_launch(void* const* d_in, const int* in_sizes, int n_in,
                              void* d_out, int out_size, void* d_ws, size_t ws_size,
                              hipStream_t stream) {
  const int* cids = (const int*)d_in[0];
  const int* eidx = (const int*)d_in[1];
  const float* eattr = (const float*)d_in[2];
  const int* sent = (const int*)d_in[3];
  const float* cemb = (const float*)d_in[4];
  const float* relemb = (const float*)d_in[5];
  const float* selfemb = (const float*)d_in[6];
  const float* W = (const float*)d_in[7];
  const float* bias = (const float*)d_in[8];

  char* ws = (char*)d_ws;
  unsigned short* xbf = (unsigned short*)ws;                         // 12,582,912 B
  unsigned short* wt = (unsigned short*)(ws + 12582912);             //  2,359,296 B
  unsigned short* xwb = (unsigned short*)(ws + 12582912 + 2359296);  // 25,165,824 B (bf16)
  float* relw2 = (float*)(ws + 12582912 + 2359296 + 25165824);       //    119,808 B
  unsigned* nmask = (unsigned*)(ws + 12582912 + 2359296 + 25165824 + 119808);  // 32 KB

  float* out = (float*)d_out;

  k_prep<<<dim3(7367), dim3(256), 0, stream>>>(cids, cemb, xbf, W, wt, relemb, selfemb,
                                               relw2, sent, nmask);
  k_gemm<<<dim3(768), dim3(256), 0, stream>>>(xbf, wt, xwb);
  k_out<<<dim3(18720), dim3(256), 0, stream>>>(cids, eidx, eattr, xwb, relw2, bias, nmask, out);
}

// Round 4
// 115.280 us; speedup vs baseline: 1.9728x; 1.3003x over previous
//
#include <hip/hip_runtime.h>
#include <stdint.h>

#define N_NODES 8192
#define N_EDGES 65536
#define N_TRIPLES (N_EDGES + N_NODES)   // 73728
#define D 768
#define D2 1536
#define NREL 38
#define BATCH 8
#define SENTN 512                        // B*S
#define OUT1_OFF ((size_t)N_TRIPLES * D)                     // 56623104
#define OUT2_OFF (OUT1_OFF + (size_t)BATCH * N_TRIPLES)      // 57212928

typedef __attribute__((ext_vector_type(8))) __bf16 bf16x8;
typedef __attribute__((ext_vector_type(4))) float f32x4;
typedef __attribute__((ext_vector_type(4))) unsigned short ushort4v;

static __device__ __forceinline__ unsigned short f2bf(float f) {
  unsigned u = __builtin_bit_cast(unsigned, f);
  u += 0x7FFFu + ((u >> 16) & 1u);
  return (unsigned short)(u >> 16);
}
static __device__ __forceinline__ float bf2f(unsigned short h) {
  return __builtin_bit_cast(float, ((unsigned)h) << 16);
}

// ================= merged prep =================
// blocks [0,6144): x = bf16(cemb[cids])           (one float4 per thread)
// blocks [6144,7296): W13T transpose->bf16
// blocks [7296,7530): relW2 PARTIALS (39 rels x 6 K-chunks of 128)
// blocks [7530,7562): node mask bits
__global__ void k_prep(const int* __restrict__ cids, const float* __restrict__ cemb,
                       unsigned short* __restrict__ xbf,
                       const float* __restrict__ W, unsigned short* __restrict__ wt,
                       const float* __restrict__ relemb, const float* __restrict__ selfemb,
                       float* __restrict__ partials,
                       const int* __restrict__ sent, unsigned int* __restrict__ nmask) {
  __shared__ __align__(16) char smraw[32 * 33 * 4];
  int b = blockIdx.x;
  if (b < 6144) {
    int t4 = b * 256 + threadIdx.x;
    int row = t4 / (D / 4);
    int c4 = t4 % (D / 4);
    int cid = cids[row];
    float4 v = ((const float4*)(cemb + (size_t)cid * D))[c4];
    ushort4v o;
    o.x = f2bf(v.x); o.y = f2bf(v.y); o.z = f2bf(v.z); o.w = f2bf(v.w);
    *(ushort4v*)(xbf + (size_t)t4 * 4) = o;
  } else if (b < 7296) {
    float (*tile)[33] = (float(*)[33])smraw;
    int idx = b - 6144;
    int kb = (idx % 24) * 32;
    int jb = (idx / 24) * 32;
    int tx = threadIdx.x % 32;
    int ty = threadIdx.x / 32;
#pragma unroll
    for (int i = 0; i < 4; ++i) {
      int k = kb + ty + i * 8;
      int j = jb + tx;
      float v = (j < D) ? W[(size_t)k * D + j] : W[(size_t)(2 * D + k) * D + (j - D)];
      tile[ty + i * 8][tx] = v;
    }
    __syncthreads();
#pragma unroll
    for (int i = 0; i < 4; ++i) {
      int j = jb + ty + i * 8;
      int k = kb + tx;
      wt[(size_t)j * D + k] = f2bf(tile[tx][ty + i * 8]);
    }
  } else if (b < 7530) {
    int idx = b - 7296;        // 0..233
    int r = idx / 6;           // 0..38
    int ch = idx % 6;          // K-chunk of 128
    const float* src = (r < NREL) ? (relemb + (size_t)r * D) : selfemb;
    int c = threadIdx.x;
    const float* W2 = W + (size_t)D * D;
    float a0 = 0.f, a1 = 0.f, a2 = 0.f;
    int k0 = ch * 128;
    for (int k = 0; k < 128; ++k) {
      float s = src[k0 + k];
      const float* wr = W2 + (size_t)(k0 + k) * D;
      a0 += s * wr[c];
      a1 += s * wr[c + 256];
      a2 += s * wr[c + 512];
    }
    float* p = partials + (size_t)idx * D;
    p[c] = a0;
    p[c + 256] = a1;
    p[c + 512] = a2;
  } else {
    int* ls = (int*)smraw;
    for (int i = threadIdx.x; i < SENTN; i += 256) ls[i] = sent[i];
    __syncthreads();
    int n = (b - 7530) * 256 + threadIdx.x;
    int cid = cids[n];
    unsigned m = 0;
#pragma unroll 16
    for (int s = 0; s < SENTN; ++s)
      m |= (ls[s] == cid) ? (1u << (s >> 6)) : 0u;
    nmask[n] = m;
  }
}

// ================= GEMM + side work =================
// blocks [0,768): Cb[8192][1536](bf16) = A * BT^T, 128x128 tile, counted-vmcnt 2-phase
// blocks [768,807): relW2 reduce (sum 6 partial chunks)
// blocks [807,1095): triple_ids + mask outputs (NT stores)
__global__ void k_gemm(const unsigned short* __restrict__ A,
                       const unsigned short* __restrict__ BT,
                       unsigned short* __restrict__ Cb,
                       const float* __restrict__ partials, float* __restrict__ relw2,
                       const int* __restrict__ cids, const int* __restrict__ eidx,
                       const float* __restrict__ eattr, const unsigned* __restrict__ nmask,
                       float* __restrict__ out) {
  __shared__ __align__(16) unsigned short lsAB[2][2][128 * 64];   // [buf][A/B]
  const int bid = blockIdx.x;
  const int tid = threadIdx.x;

  if (bid >= 768) {
    if (bid < 807) {
      // ---- relW2 reduce: relw2[r][c] = sum_ch partials[r*6+ch][c] ----
      int r = bid - 768;
      int c = tid;
      const float* p = partials + (size_t)r * 6 * D;
#pragma unroll
      for (int j = 0; j < 3; ++j) {
        int cc = c + j * 256;
        float s = 0.f;
#pragma unroll
        for (int ch = 0; ch < 6; ++ch) s += p[(size_t)ch * D + cc];
        relw2[(size_t)r * D + cc] = s;
      }
    } else {
      // ---- triple ids + mask ----
      int t = (bid - 807) * 256 + tid;
      int h, tl;
      float rel;
      if (t < N_EDGES) {
        h = eidx[t];
        tl = eidx[N_EDGES + t];
        rel = (float)(int)eattr[2 * t];
      } else {
        h = t - N_EDGES;
        tl = h;
        rel = (float)NREL;
      }
      float* o2 = out + OUT2_OFF + (size_t)t * 3;
      __builtin_nontemporal_store((float)cids[h], o2 + 0);
      __builtin_nontemporal_store(rel, o2 + 1);
      __builtin_nontemporal_store((float)cids[tl], o2 + 2);
      unsigned m = nmask[h] | nmask[tl];
      float* o1 = out + OUT1_OFF;
#pragma unroll
      for (int bb = 0; bb < BATCH; ++bb)
        __builtin_nontemporal_store(((m >> bb) & 1u) ? 1.0f : 0.0f,
                                    o1 + (size_t)bb * N_TRIPLES + t);
    }
    return;
  }

  const int lane = tid & 63;
  const int wid = tid >> 6;
  const int wr = wid >> 1, wc = wid & 1;

  // XCD-aware bijective swizzle: 768 blocks, 96 per XCD.
  const int swz = (bid & 7) * 96 + (bid >> 3);
  const int arow0 = (swz / 12) * 128;
  const int bcol0 = (swz % 12) * 128;

  f32x4 acc[4][4] = {};

  const int rloc = tid >> 3;                       // 0..31: row within 32-row chunk
  const int gchunk = (tid & 7) ^ (rloc & 7);       // swizzled source col-chunk
  const unsigned short* ga = A + (size_t)(arow0 + rloc) * D + gchunk * 8;
  const unsigned short* gb = BT + (size_t)(bcol0 + rloc) * D + gchunk * 8;
  const int lbo = (tid & ~63) * 8;                 // wave-uniform LDS elem offset

  const int lr = lane & 15;
  const int hi = lane >> 4;

#define STAGE(BUF, K0)                                                                 \
  {                                                                                    \
    unsigned short* dA = &lsAB[BUF][0][lbo];                                           \
    unsigned short* dB = &lsAB[BUF][1][lbo];                                           \
    _Pragma("unroll") for (int c = 0; c < 4; ++c) {                                    \
      __builtin_amdgcn_global_load_lds(                                                \
          (const __attribute__((address_space(1))) void*)(ga + (size_t)c * 32 * D + (K0)), \
          (__attribute__((address_space(3))) void*)(dA + c * 2048), 16, 0, 0);         \
      __builtin_amdgcn_global_load_lds(                                                \
          (const __attribute__((address_space(1))) void*)(gb + (size_t)c * 32 * D + (K0)), \
          (__attribute__((address_space(3))) void*)(dB + c * 2048), 16, 0, 0);         \
    }                                                                                  \
  }

#define COMPUTE(BUF)                                                                   \
  {                                                                                    \
    const unsigned short* sA = lsAB[BUF][0];                                           \
    const unsigned short* sB = lsAB[BUF][1];                                           \
    _Pragma("unroll") for (int kk = 0; kk < 2; ++kk) {                                 \
      const int swc = ((kk * 4 + hi) ^ (lr & 7)) * 8;                                  \
      bf16x8 af[4], bfr[4];                                                            \
      _Pragma("unroll") for (int m = 0; m < 4; ++m)                                    \
          af[m] = *(const bf16x8*)(sA + (wr * 64 + m * 16 + lr) * 64 + swc);           \
      _Pragma("unroll") for (int n = 0; n < 4; ++n)                                    \
          bfr[n] = *(const bf16x8*)(sB + (wc * 64 + n * 16 + lr) * 64 + swc);          \
      _Pragma("unroll") for (int m = 0; m < 4; ++m)                                    \
          _Pragma("unroll") for (int n = 0; n < 4; ++n)                                \
              acc[m][n] = __builtin_amdgcn_mfma_f32_16x16x32_bf16(af[m], bfr[n],       \
                                                                  acc[m][n], 0, 0, 0); \
    }                                                                                  \
  }

  // Counted-vmcnt 2-phase: raw barriers, NEVER drain vmcnt to 0 in steady state.
  // In-flight: 16 loads (2 tiles x 8/wave); vmcnt(8) => oldest tile's loads done.
  STAGE(0, 0)
  STAGE(1, 64)
#pragma unroll
  for (int t = 0; t < 12; ++t) {
    if (t < 11) { asm volatile("s_waitcnt vmcnt(8)" ::: "memory"); }
    else        { asm volatile("s_waitcnt vmcnt(0)" ::: "memory"); }
    __builtin_amdgcn_s_barrier();      // tile t ready in all waves
    if (t & 1) COMPUTE(1) else COMPUTE(0)
    asm volatile("" ::: "memory");     // pin LDS reads before the reuse barrier
    __builtin_amdgcn_s_barrier();      // all waves done reading buf[t&1]
    if (t + 2 < 12) { if (t & 1) STAGE(1, (t + 2) * 64) else STAGE(0, (t + 2) * 64) }
  }
#undef STAGE
#undef COMPUTE

  const int crow = hi * 4;
  const int ccol = lr;
#pragma unroll
  for (int m = 0; m < 4; ++m) {
    int row = arow0 + wr * 64 + m * 16 + crow;
#pragma unroll
    for (int n = 0; n < 4; ++n) {
      int col = bcol0 + wc * 64 + n * 16 + ccol;
      unsigned short* cp = Cb + (size_t)row * D2 + col;
#pragma unroll
      for (int r = 0; r < 4; ++r)
        cp[(size_t)r * D2] = f2bf(acc[m][n][r]);
    }
  }
}

// ================= encoded output =================
// encoded[t] = xw1[head] + w*relW2[rel] + xw3[tail] + b   (4 triples/block, NT stores)
__global__ void k_out(const int* __restrict__ eidx, const float* __restrict__ eattr,
                      const unsigned short* __restrict__ xwb, const float* __restrict__ relw2,
                      const float* __restrict__ bias, float* __restrict__ out) {
  int wid = threadIdx.x >> 6;
  int lane = threadIdx.x & 63;
  int t = blockIdx.x * 4 + wid;
  const ushort4v *r1, *r3;
  const f32x4* rw;
  float w;
  if (t < N_EDGES) {
    int h = eidx[t];
    int tl = eidx[N_EDGES + t];
    int rel = (int)eattr[2 * t];
    w = eattr[2 * t + 1];
    r1 = (const ushort4v*)(xwb + (size_t)h * D2);
    r3 = (const ushort4v*)(xwb + (size_t)tl * D2 + D);
    rw = (const f32x4*)(relw2 + (size_t)rel * D);
  } else {
    int i = t - N_EDGES;
    w = 1.f;
    r1 = (const ushort4v*)(xwb + (size_t)i * D2);
    r3 = (const ushort4v*)(xwb + (size_t)i * D2 + D);
    rw = (const f32x4*)(relw2 + (size_t)NREL * D);
  }
  const f32x4* bv = (const f32x4*)bias;
  f32x4* o = (f32x4*)(out + (size_t)t * D);
#pragma unroll
  for (int j = 0; j < 3; ++j) {
    int c4 = j * 64 + lane;
    ushort4v a4 = r1[c4], x4 = r3[c4];
    f32x4 c = rw[c4], dd = bv[c4];
    f32x4 res;
    res.x = bf2f(a4.x) + w * c.x + bf2f(x4.x) + dd.x;
    res.y = bf2f(a4.y) + w * c.y + bf2f(x4.y) + dd.y;
    res.z = bf2f(a4.z) + w * c.z + bf2f(x4.z) + dd.z;
    res.w = bf2f(a4.w) + w * c.w + bf2f(x4.w) + dd.w;
    __builtin_nontemporal_store(res, &o[c4]);
  }
}

extern "C" void kernel_launch(void* const* d_in, const int* in_sizes, int n_in,
                              void* d_out, int out_size, void* d_ws, size_t ws_size,
                              hipStream_t stream) {
  const int* cids = (const int*)d_in[0];
  const int* eidx = (const int*)d_in[1];
  const float* eattr = (const float*)d_in[2];
  const int* sent = (const int*)d_in[3];
  const float* cemb = (const float*)d_in[4];
  const float* relemb = (const float*)d_in[5];
  const float* selfemb = (const float*)d_in[6];
  const float* W = (const float*)d_in[7];
  const float* bias = (const float*)d_in[8];

  char* ws = (char*)d_ws;
  unsigned short* xbf = (unsigned short*)ws;                         // 12,582,912 B
  unsigned short* wt = (unsigned short*)(ws + 12582912);             //  2,359,296 B
  unsigned short* xwb = (unsigned short*)(ws + 12582912 + 2359296);  // 25,165,824 B (bf16)
  float* relw2 = (float*)(ws + 12582912 + 2359296 + 25165824);       //    119,808 B
  unsigned* nmask = (unsigned*)(ws + 12582912 + 2359296 + 25165824 + 119808);  // 32,768 B
  float* partials = (float*)(ws + 12582912 + 2359296 + 25165824 + 119808 + 32768);  // 718,848 B

  float* out = (float*)d_out;

  k_prep<<<dim3(7562), dim3(256), 0, stream>>>(cids, cemb, xbf, W, wt, relemb, selfemb,
                                               partials, sent, nmask);
  k_gemm<<<dim3(1095), dim3(256), 0, stream>>>(xbf, wt, xwb, partials, relw2,
                                               cids, eidx, eattr, nmask, out);
  k_out<<<dim3(18432), dim3(256), 0, stream>>>(eidx, eattr, xwb, relw2, bias, out);
}